// Round 10
// baseline (352.263 us; speedup 1.0000x reference)
//
#include <hip/hip_runtime.h>
#include <math.h>

#define BATCH 8
#define SEQ 2048
#define DIM 512
#define MTOT (BATCH*SEQ)
#define HID 30

typedef short bf16x8 __attribute__((ext_vector_type(8)));
typedef float f32x4 __attribute__((ext_vector_type(4)));

__device__ __forceinline__ unsigned short f2bf(float f) {
  unsigned int u = __float_as_uint(f);
  unsigned int r = (u + 0x7FFFu + ((u >> 16) & 1u)) >> 16;  // RNE
  return (unsigned short)r;
}
__device__ __forceinline__ float bf2f(unsigned short u) {
  return __uint_as_float((unsigned int)u << 16);
}

__device__ __forceinline__ void gload_lds16(const void* g, void* l) {
  __builtin_amdgcn_global_load_lds((const __attribute__((address_space(1))) void*)g,
                                   (__attribute__((address_space(3))) void*)l, 16, 0, 0);
}

// ---- 256x256 tile GEMM core: C = A * B^T, row-major [256][K=512] bf16.
// BK=32, 8 waves (2x4), 2-slot LDS ring (64 KB -> 2 blocks/CU: cross-block overlap
// covers the per-tile vmcnt(0) drain, m97/m114 regime). ONE barrier per K-tile.
// Zero-conflict macro-row layout (verified): row r = 8x16B chunks (A: ss0-3, B: ss4-7),
// physical slot = ss ^ (r&7); staged linearly via global_load_lds, pre-swizzled source.
// WAR safety (2-slot): stage target (kt+1)&1 holds tile kt-1, whose reads were
// lgkm-consumed before each wave's MFMA at kt-1, hence before the kt-1 end barrier.
__device__ __forceinline__ void gemm256_core(const unsigned short* __restrict__ gA,
                                             const unsigned short* __restrict__ gB,
                                             char* smem, f32x4 (&acc)[8][4]) {
  const int t = threadIdx.x;
  const int lane = t & 63;
  const int w = t >> 6;
  const int wr = w >> 2, wc = w & 3;
  const int lr = lane & 15, kc = lane >> 4;
  const int ss = (t & 7) ^ ((t >> 3) & 7);
  const unsigned short* gsrc = (ss < 4 ? gA : gB) + (size_t)(t >> 3) * DIM + (ss & 3) * 8;
  const uint32_t dbase = (uint32_t)(t & 448) * 16;  // wave-uniform base; HW adds lane*16

  auto stage = [&](int slot, int kt) {
#pragma unroll
    for (int q = 0; q < 4; ++q)
      gload_lds16(gsrc + (size_t)(q * 64) * DIM + kt * 32,
                  smem + slot * 32768 + q * 8192 + dbase);
  };

  stage(0, 0);
  asm volatile("s_waitcnt vmcnt(0)" ::: "memory");
  __builtin_amdgcn_s_barrier();
  asm volatile("" ::: "memory");

#pragma unroll
  for (int kt = 0; kt < 16; ++kt) {
    const char* Ab = smem + (kt & 1) * 32768;
    bf16x8 bfr[4], af[4], af2[4];
#pragma unroll
    for (int j = 0; j < 4; ++j) {
      int r = wc * 64 + j * 16 + lr;
      bfr[j] = *(const bf16x8*)(Ab + r * 128 + (((4 + kc) ^ (r & 7)) << 4));
    }
#pragma unroll
    for (int i = 0; i < 4; ++i) {
      int r = wr * 128 + i * 16 + lr;
      af[i] = *(const bf16x8*)(Ab + r * 128 + ((kc ^ (r & 7)) << 4));
    }
    __builtin_amdgcn_sched_barrier(0);
#pragma unroll
    for (int i = 0; i < 4; ++i) {
      int r = wr * 128 + (i + 4) * 16 + lr;
      af2[i] = *(const bf16x8*)(Ab + r * 128 + ((kc ^ (r & 7)) << 4));
    }
    __builtin_amdgcn_sched_barrier(0);
    if (kt < 15) stage((kt + 1) & 1, kt + 1);
    __builtin_amdgcn_sched_barrier(0);
    __builtin_amdgcn_s_setprio(1);
#pragma unroll
    for (int i = 0; i < 4; ++i)   // compiler emits lgkmcnt(4): af2 still in flight
#pragma unroll
      for (int j = 0; j < 4; ++j)
        acc[i][j] = __builtin_amdgcn_mfma_f32_16x16x32_bf16(af[i], bfr[j], acc[i][j], 0, 0, 0);
    __builtin_amdgcn_s_setprio(0);
    __builtin_amdgcn_sched_barrier(0);
    __builtin_amdgcn_s_setprio(1);
#pragma unroll
    for (int i = 0; i < 4; ++i)   // compiler emits lgkmcnt(0)
#pragma unroll
      for (int j = 0; j < 4; ++j)
        acc[i + 4][j] = __builtin_amdgcn_mfma_f32_16x16x32_bf16(af2[i], bfr[j], acc[i + 4][j], 0, 0, 0);
    __builtin_amdgcn_s_setprio(0);
    __builtin_amdgcn_sched_barrier(0);
    asm volatile("s_waitcnt vmcnt(0)" ::: "memory");  // tile kt+1 landed (issued this tile)
    __builtin_amdgcn_s_barrier();
    asm volatile("" ::: "memory");
  }
}

// ---- 128x128 tile core: 4 waves (2x2), BK=32, 2-slot ring (32 KB -> 4 blocks/CU). ----
__device__ __forceinline__ void gemm128_core(const unsigned short* __restrict__ gA,
                                             const unsigned short* __restrict__ gB,
                                             char* smem, f32x4 (&acc)[4][4]) {
  const int t = threadIdx.x;  // 0..255
  const int lane = t & 63;
  const int w = t >> 6;
  const int wr = w >> 1, wc = w & 1;
  const int lr = lane & 15, kc = lane >> 4;
  const int ss = (t & 7) ^ ((t >> 3) & 7);
  const unsigned short* gsrc = (ss < 4 ? gA : gB) + (size_t)(t >> 3) * DIM + (ss & 3) * 8;
  const uint32_t dbase = (uint32_t)(t & 192) * 16;

  auto stage = [&](int slot, int kt) {
#pragma unroll
    for (int q = 0; q < 4; ++q)
      gload_lds16(gsrc + (size_t)(q * 32) * DIM + kt * 32,
                  smem + slot * 16384 + q * 4096 + dbase);
  };

  stage(0, 0);
  asm volatile("s_waitcnt vmcnt(0)" ::: "memory");
  __builtin_amdgcn_s_barrier();
  asm volatile("" ::: "memory");

#pragma unroll
  for (int kt = 0; kt < 16; ++kt) {
    const char* Ab = smem + (kt & 1) * 16384;
    bf16x8 bfr[4], af[4];
#pragma unroll
    for (int j = 0; j < 4; ++j) {
      int r = wc * 64 + j * 16 + lr;
      bfr[j] = *(const bf16x8*)(Ab + r * 128 + (((4 + kc) ^ (r & 7)) << 4));
    }
#pragma unroll
    for (int i = 0; i < 4; ++i) {
      int r = wr * 64 + i * 16 + lr;
      af[i] = *(const bf16x8*)(Ab + r * 128 + ((kc ^ (r & 7)) << 4));
    }
    __builtin_amdgcn_sched_barrier(0);
    if (kt < 15) stage((kt + 1) & 1, kt + 1);
    __builtin_amdgcn_sched_barrier(0);
    __builtin_amdgcn_s_setprio(1);
#pragma unroll
    for (int i = 0; i < 4; ++i)
#pragma unroll
      for (int j = 0; j < 4; ++j)
        acc[i][j] = __builtin_amdgcn_mfma_f32_16x16x32_bf16(af[i], bfr[j], acc[i][j], 0, 0, 0);
    __builtin_amdgcn_s_setprio(0);
    __builtin_amdgcn_sched_barrier(0);
    asm volatile("s_waitcnt vmcnt(0)" ::: "memory");
    __builtin_amdgcn_s_barrier();
    asm volatile("" ::: "memory");
  }
}

// ---- k_prep: 0-255 gmat 32x32 | 256-287 u | 288-319 wv2 | 320 consts | 321+ R->bf16 ----
__global__ __launch_bounds__(256) void k_prep(
    const float* __restrict__ R, const float* __restrict__ Wq, const float* __restrict__ Wk,
    const float* __restrict__ Wv, const float* __restrict__ bq, const float* __restrict__ bv,
    const float* __restrict__ W1, const float* __restrict__ b1,
    const float* __restrict__ W2, const float* __restrict__ b2,
    unsigned short* __restrict__ Gt, unsigned short* __restrict__ Rb16,
    float* __restrict__ u, float* __restrict__ wv2, float* __restrict__ consts) {
  __shared__ __align__(16) float As[16][34];
  __shared__ __align__(16) float Bs[16][34];
  __shared__ float vecs[512];
  __shared__ float red2[16][17];
  const int bid = blockIdx.x;
  const int t = threadIdx.x;

  if (bid >= 321) {  // R -> bf16 convert only
    size_t base = ((size_t)(bid - 321) * 256 + t) * 8;
    float4 r0 = *(const float4*)&R[base];
    float4 r1 = *(const float4*)&R[base + 4];
    ushort4 lo, hi;
    lo.x = f2bf(r0.x); lo.y = f2bf(r0.y); lo.z = f2bf(r0.z); lo.w = f2bf(r0.w);
    hi.x = f2bf(r1.x); hi.y = f2bf(r1.y); hi.z = f2bf(r1.z); hi.w = f2bf(r1.w);
    *(ushort4*)&Rb16[base] = lo;
    *(ushort4*)&Rb16[base + 4] = hi;
    return;
  }
  if (bid < 256) {  // Gt[q2][q1] = sum_d Wq[d][q1] Wk[d][q2], 32x32 tiles
    int tm = t & 15, tn = t >> 4;
    int q1b = (bid & 15) * 32, q2b = (bid >> 4) * 32;
    int lk = t >> 4, lc = (t & 15) * 2;
    float acc[2][2] = {};
    for (int kb = 0; kb < DIM; kb += 16) {
      *(float2*)&As[lk][lc] = *(const float2*)&Wq[(size_t)(kb + lk) * DIM + q1b + lc];
      *(float2*)&Bs[lk][lc] = *(const float2*)&Wk[(size_t)(kb + lk) * DIM + q2b + lc];
      __syncthreads();
#pragma unroll
      for (int k = 0; k < 16; ++k) {
        float a0 = As[k][tm * 2], a1 = As[k][tm * 2 + 1];
        float b0 = Bs[k][tn * 2], b1v = Bs[k][tn * 2 + 1];
        acc[0][0] = fmaf(a0, b0, acc[0][0]); acc[0][1] = fmaf(a0, b1v, acc[0][1]);
        acc[1][0] = fmaf(a1, b0, acc[1][0]); acc[1][1] = fmaf(a1, b1v, acc[1][1]);
      }
      __syncthreads();
    }
#pragma unroll
    for (int i = 0; i < 2; ++i)
#pragma unroll
      for (int j = 0; j < 2; ++j)
        Gt[(size_t)(q2b + tn * 2 + j) * DIM + (q1b + tm * 2 + i)] = f2bf(acc[i][j]);
    return;
  }
  if (bid < 320) {
    bool isU = bid < 288;
    int qb = (bid - (isU ? 256 : 288)) * 16;
    if (isU) {
      vecs[t] = bq[t];
      vecs[t + 256] = bq[t + 256];
    } else {
      for (int d = t; d < DIM; d += 256) {
        float s = 0.f;
        for (int j = 0; j < HID; ++j) s = fmaf(W2[j], W1[(size_t)j * DIM + d], s);
        vecs[d] = s;
      }
    }
    __syncthreads();
    const float* M = isU ? Wk : Wv;
    int ql = t & 15, ds = t >> 4;
    float s = 0.f;
#pragma unroll 8
    for (int i = 0; i < 32; ++i) {
      int d = ds * 32 + i;
      s = fmaf(vecs[d], M[(size_t)d * DIM + qb + ql], s);
    }
    red2[ds][ql] = s;
    __syncthreads();
    if (t < 16) {
      float r = 0.f;
#pragma unroll
      for (int k = 0; k < 16; ++k) r += red2[k][t];
      (isU ? u : wv2)[qb + t] = r;
    }
    return;
  }
  // bid == 320: const1 = bv.w12 ; c0 = W2.b1 + b2
  {
    for (int d = t; d < DIM; d += 256) {
      float s = 0.f;
      for (int j = 0; j < HID; ++j) s = fmaf(W2[j], W1[(size_t)j * DIM + d], s);
      vecs[d] = s;
    }
    __syncthreads();
    float* red = (float*)red2;
    red[t] = bv[t] * vecs[t] + bv[t + 256] * vecs[t + 256];
    __syncthreads();
    for (int o = 128; o > 0; o >>= 1) {
      if (t < o) red[t] += red[t + o];
      __syncthreads();
    }
    if (t == 0) {
      consts[0] = red[0];
      float s = b2[0];
      for (int j = 0; j < HID; ++j) s = fmaf(W2[j], b1[j], s);
      consts[1] = s;
    }
  }
}

// ---- k_projT: T = Rb16 @ Gt^T + u (128x128 core); blockIdx.y==0 also computes vw ----
__global__ __launch_bounds__(256, 4) void k_projT(const unsigned short* __restrict__ Rb16,
                                                  const unsigned short* __restrict__ Gt,
                                                  const float* __restrict__ u,
                                                  const float* __restrict__ wv2,
                                                  unsigned short* __restrict__ Tb16,
                                                  float* __restrict__ vw) {
  __shared__ __align__(16) char smem[32768];
  __shared__ float u_lds[128];
  int t = threadIdx.x;
  size_t rowb = (size_t)blockIdx.x * 128;
  int colb = blockIdx.y * 128;
  if (t < 128) u_lds[t] = u[colb + t];
  f32x4 acc[4][4] = {};
  gemm128_core(Rb16 + rowb * DIM, Gt + (size_t)colb * DIM, smem, acc);
  int lane = t & 63, w = t >> 6, wr = w >> 1, wc = w & 1;
  int lr = lane & 15, kq = lane >> 4;
#pragma unroll
  for (int i = 0; i < 4; ++i)
#pragma unroll
    for (int j = 0; j < 4; ++j)
#pragma unroll
      for (int r = 0; r < 4; ++r) {
        int row = wr * 64 + i * 16 + kq * 4 + r;
        int col = wc * 64 + j * 16 + lr;
        Tb16[(rowb + row) * DIM + colb + col] = f2bf(acc[i][j][r] + u_lds[col]);
      }
  if (blockIdx.y == 0) {  // vw[n] = Rb16[n].wv2 (const1 folded into k_final)
    float* wv2s = (float*)smem;  // reuse slot 0 after all reads done
    __syncthreads();
    if (t < 256) { wv2s[t] = wv2[t]; wv2s[t + 256] = wv2[t + 256]; }
    __syncthreads();
    int row = (int)rowb + (t >> 1);
    const unsigned short* rp = Rb16 + (size_t)row * DIM + (t & 1) * 256;
    const float* wp = wv2s + (t & 1) * 256;
    float s = 0.f;
#pragma unroll 8
    for (int i = 0; i < 32; ++i) {
      bf16x8 v = *(const bf16x8*)(rp + i * 8);
#pragma unroll
      for (int e = 0; e < 8; ++e) s = fmaf(bf2f((unsigned short)v[e]), wp[i * 8 + e], s);
    }
    s += __shfl_xor(s, 1);
    if ((t & 1) == 0) vw[row] = s;
  }
}

// ---- k_qk: S = T @ R^T (256x256 core) + exp + fused s1/den partials ----
__global__ __launch_bounds__(512, 4) void k_qk(const unsigned short* __restrict__ Tb16,
                                               const unsigned short* __restrict__ Rb16,
                                               const float* __restrict__ vw,
                                               float* __restrict__ part_s1,
                                               float* __restrict__ part_den) {
  __shared__ __align__(16) char smem[65536];
  __shared__ float vw_lds[256];
  __shared__ float red_s1[4][256], red_den[4][256];
  int t = threadIdx.x;
  // XCD swizzle: each XCD owns one batch (T+R panels fit its 4MB L2)
  int orig = blockIdx.x;
  int wgid = (orig & 7) * 64 + (orig >> 3);
  int b = wgid >> 6;
  int nb = ((wgid >> 3) & 7) * 256;
  int mb = (wgid & 7) * 256;
  if (t < 256) vw_lds[t] = vw[b * SEQ + mb + t];
  f32x4 acc[8][4] = {};
  gemm256_core(Tb16 + ((size_t)b * SEQ + nb) * DIM,
               Rb16 + ((size_t)b * SEQ + mb) * DIM, smem, acc);
  int lane = t & 63, w = t >> 6, wr = w >> 2, wc = w & 3;
  int lr = lane & 15, kq = lane >> 4;
  const float rs = 0.044194173824159216f;  // 1/sqrt(512)
  float vwl[4];
#pragma unroll
  for (int j = 0; j < 4; ++j) vwl[j] = vw_lds[wc * 64 + j * 16 + lr];
#pragma unroll
  for (int i = 0; i < 8; ++i) {
#pragma unroll
    for (int r = 0; r < 4; ++r) {
      float sa = 0.f, sd = 0.f;
#pragma unroll
      for (int j = 0; j < 4; ++j) {
        float e = __expf(acc[i][j][r] * rs);
        sa = fmaf(e, vwl[j], sa);
        sd += e;
      }
#pragma unroll
      for (int m = 1; m < 16; m <<= 1) { sa += __shfl_xor(sa, m); sd += __shfl_xor(sd, m); }
      if (lr == 0) {
        int rl = wr * 128 + i * 16 + kq * 4 + r;
        red_s1[wc][rl] = sa;
        red_den[wc][rl] = sd;
      }
    }
  }
  __syncthreads();
  if (t < 256) {
    size_t o = ((size_t)b * 8 + (mb >> 8)) * SEQ + nb + t;
    part_s1[o] = red_s1[0][t] + red_s1[1][t] + red_s1[2][t] + red_s1[3][t];
    part_den[o] = red_den[0][t] + red_den[1][t] + red_den[2][t] + red_den[3][t];
  }
}

// ---- k_final: winner = s1/den + const1 + c0 ----
__global__ void k_final(const float* __restrict__ part_s1, const float* __restrict__ part_den,
                        const float* __restrict__ consts, float* __restrict__ out) {
  int n = blockIdx.x * 256 + threadIdx.x;
  int b = n >> 11, nn = n & 2047;
  float s1 = 0.f, dn = 0.f;
#pragma unroll
  for (int i = 0; i < 8; ++i) {
    size_t o = ((size_t)b * 8 + i) * SEQ + nn;
    s1 += part_s1[o];
    dn += part_den[o];
  }
  out[n] = s1 / dn + consts[0] + consts[1];
}

extern "C" void kernel_launch(void* const* d_in, const int* in_sizes, int n_in,
                              void* d_out, int out_size, void* d_ws, size_t ws_size,
                              hipStream_t stream) {
  const float* R  = (const float*)d_in[0];
  const float* Wq = (const float*)d_in[1];
  const float* bq = (const float*)d_in[2];
  const float* Wk = (const float*)d_in[3];
  const float* bk = (const float*)d_in[4];  // cancels in row-softmax
  const float* Wv = (const float*)d_in[5];
  const float* bv = (const float*)d_in[6];
  const float* W1 = (const float*)d_in[7];
  const float* b1 = (const float*)d_in[8];
  const float* W2 = (const float*)d_in[9];
  const float* b2 = (const float*)d_in[10];
  (void)bk;
  float* out = (float*)d_out;

  char* p = (char*)d_ws;
  unsigned short* Rb16 = (unsigned short*)p; p += (size_t)MTOT * DIM * 2;
  unsigned short* Tb16 = (unsigned short*)p; p += (size_t)MTOT * DIM * 2;
  unsigned short* Gt   = (unsigned short*)p; p += (size_t)DIM * DIM * 2;
  float* part_s1  = (float*)p; p += (size_t)BATCH * 8 * SEQ * 4;
  float* part_den = (float*)p; p += (size_t)BATCH * 8 * SEQ * 4;
  float* u      = (float*)p; p += DIM * 4;
  float* wv2    = (float*)p; p += DIM * 4;
  float* vw     = (float*)p; p += MTOT * 4;
  float* consts = (float*)p; p += 16;

  hipLaunchKernelGGL(k_prep, dim3(321 + MTOT * DIM / (256 * 8)), dim3(256), 0, stream,
                     R, Wq, Wk, Wv, bq, bv, W1, b1, W2, b2, Gt, Rb16, u, wv2, consts);
  hipLaunchKernelGGL(k_projT, dim3(MTOT / 128, DIM / 128), dim3(256), 0, stream,
                     Rb16, Gt, u, wv2, Tb16, vw);
  hipLaunchKernelGGL(k_qk, dim3(512), dim3(512), 0, stream, Tb16, Rb16, vw, part_s1, part_den);
  hipLaunchKernelGGL(k_final, dim3(MTOT / 256), dim3(256), 0, stream,
                     part_s1, part_den, consts, out);
}

// Round 11
// 114.393 us; speedup vs baseline: 3.0794x; 3.0794x over previous
//
#include <hip/hip_runtime.h>
#include <math.h>

#define BATCH 8
#define SEQ 2048
#define DIM 512
#define MTOT (BATCH*SEQ)
#define HID 30

typedef short bf16x8 __attribute__((ext_vector_type(8)));
typedef float f32x4 __attribute__((ext_vector_type(4)));
typedef float f32x16 __attribute__((ext_vector_type(16)));

__device__ __forceinline__ unsigned short f2bf(float f) {
  unsigned int u = __float_as_uint(f);
  unsigned int r = (u + 0x7FFFu + ((u >> 16) & 1u)) >> 16;  // RNE
  return (unsigned short)r;
}
__device__ __forceinline__ float bf2f(unsigned short u) {
  return __uint_as_float((unsigned int)u << 16);
}

__device__ __forceinline__ void gload_lds16(const void* g, void* l) {
  __builtin_amdgcn_global_load_lds((const __attribute__((address_space(1))) void*)g,
                                   (__attribute__((address_space(3))) void*)l, 16, 0, 0);
}

// ---- 256x256 tile GEMM core, 32x32x16 MFMA variant: C = A * B^T, row-major [256][512] bf16.
// BK=32, 8 waves (2 row x 4 col), per-wave 128x64 = 4 row-frags x 2 col-frags of 32x32,
// acc = f32x16[4][2]. 3-slot LDS ring, counted vmcnt(4), ONE barrier per K-tile
// (identical staging/swizzle/sync to the verified R8 16x16 core; only fragment shape,
// MFMA opcode, and read addressing change).
// Fragment maps: A/B row=lane&31, k=(lane>>5)*8+e; C/D col=lane&31,
// row=(reg&3)+8*(reg>>2)+4*(lane>>5)  [m74/m101-verified].
// Per k-tile: 2 ksteps of K=16; A chunk = s*2+(lane>>5), B chunk = 4 + that;
// physical slot = chunk ^ (row&7) (same zero-conflict macro-row geometry).
__device__ __forceinline__ void gemm256_core32(const unsigned short* __restrict__ gA,
                                               const unsigned short* __restrict__ gB,
                                               char* smem, f32x16 (&acc)[4][2]) {
  const int t = threadIdx.x;
  const int lane = t & 63;
  const int w = t >> 6;
  const int wr = w >> 2, wc = w & 3;
  const int lm = lane & 31;    // row/col within 32-frag
  const int kh = lane >> 5;    // k-half
  const int ss = (t & 7) ^ ((t >> 3) & 7);
  const unsigned short* gsrc = (ss < 4 ? gA : gB) + (size_t)(t >> 3) * DIM + (ss & 3) * 8;
  const uint32_t dbase = (uint32_t)(t & 448) * 16;  // wave-uniform base; HW adds lane*16

  auto stage = [&](int slot, int kt) {
#pragma unroll
    for (int q = 0; q < 4; ++q)
      gload_lds16(gsrc + (size_t)(q * 64) * DIM + kt * 32,
                  smem + slot * 32768 + q * 8192 + dbase);
  };

  stage(0, 0); stage(1, 1);
  asm volatile("s_waitcnt vmcnt(4)" ::: "memory");
  __builtin_amdgcn_s_barrier();
  asm volatile("" ::: "memory");

#pragma unroll
  for (int kt = 0; kt < 16; ++kt) {
    const char* Ab = smem + (kt % 3) * 32768;
    const int fslot = (kt + 2) % 3;
    const int src = (kt + 2 < 16) ? (kt + 2) : 15;  // dummy tail keeps vmcnt uniform
    bf16x8 bfr[2][2], af0[4], af1[4];
#pragma unroll
    for (int s = 0; s < 2; ++s)
#pragma unroll
      for (int fj = 0; fj < 2; ++fj) {
        int r = wc * 64 + fj * 32 + lm;
        int kc = s * 2 + kh;
        bfr[s][fj] = *(const bf16x8*)(Ab + r * 128 + (((4 + kc) ^ (r & 7)) << 4));
      }
#pragma unroll
    for (int fi = 0; fi < 4; ++fi) {
      int r = wr * 128 + fi * 32 + lm;
      af0[fi] = *(const bf16x8*)(Ab + r * 128 + ((kh ^ (r & 7)) << 4));
    }
    __builtin_amdgcn_sched_barrier(0);
#pragma unroll
    for (int fi = 0; fi < 4; ++fi) {
      int r = wr * 128 + fi * 32 + lm;
      af1[fi] = *(const bf16x8*)(Ab + r * 128 + (((2 + kh) ^ (r & 7)) << 4));
    }
    __builtin_amdgcn_sched_barrier(0);
    stage(fslot, src);
    __builtin_amdgcn_sched_barrier(0);
    __builtin_amdgcn_s_setprio(1);
#pragma unroll
    for (int fi = 0; fi < 4; ++fi)   // compiler waits only af0/bfr; af1 in flight
#pragma unroll
      for (int fj = 0; fj < 2; ++fj)
        acc[fi][fj] = __builtin_amdgcn_mfma_f32_32x32x16_bf16(af0[fi], bfr[0][fj], acc[fi][fj], 0, 0, 0);
    __builtin_amdgcn_s_setprio(0);
    __builtin_amdgcn_sched_barrier(0);
    __builtin_amdgcn_s_setprio(1);
#pragma unroll
    for (int fi = 0; fi < 4; ++fi)
#pragma unroll
      for (int fj = 0; fj < 2; ++fj)
        acc[fi][fj] = __builtin_amdgcn_mfma_f32_32x32x16_bf16(af1[fi], bfr[1][fj], acc[fi][fj], 0, 0, 0);
    __builtin_amdgcn_s_setprio(0);
    __builtin_amdgcn_sched_barrier(0);
    asm volatile("s_waitcnt vmcnt(4)" ::: "memory");
    __builtin_amdgcn_s_barrier();
    asm volatile("" ::: "memory");
  }
}

// ---- 128x128 tile core: 4 waves (2x2), BK=32, 3-slot ring (16KB/slot), 1 barrier/tile.
// (R8-verified, unchanged)
__device__ __forceinline__ void gemm128_core(const unsigned short* __restrict__ gA,
                                             const unsigned short* __restrict__ gB,
                                             char* smem, f32x4 (&acc)[4][4]) {
  const int t = threadIdx.x;  // 0..255
  const int lane = t & 63;
  const int w = t >> 6;
  const int wr = w >> 1, wc = w & 1;
  const int lr = lane & 15, kc = lane >> 4;
  const int ss = (t & 7) ^ ((t >> 3) & 7);
  const unsigned short* gsrc = (ss < 4 ? gA : gB) + (size_t)(t >> 3) * DIM + (ss & 3) * 8;
  const uint32_t dbase = (uint32_t)(t & 192) * 16;

  auto stage = [&](int slot, int kt) {
#pragma unroll
    for (int q = 0; q < 4; ++q)
      gload_lds16(gsrc + (size_t)(q * 32) * DIM + kt * 32,
                  smem + slot * 16384 + q * 4096 + dbase);
  };

  stage(0, 0); stage(1, 1);
  asm volatile("s_waitcnt vmcnt(4)" ::: "memory");
  __builtin_amdgcn_s_barrier();
  asm volatile("" ::: "memory");

#pragma unroll
  for (int kt = 0; kt < 16; ++kt) {
    const char* Ab = smem + (kt % 3) * 16384;
    const int fslot = (kt + 2) % 3;
    const int src = (kt + 2 < 16) ? (kt + 2) : 15;
    bf16x8 bfr[4], af[4];
#pragma unroll
    for (int j = 0; j < 4; ++j) {
      int r = wc * 64 + j * 16 + lr;
      bfr[j] = *(const bf16x8*)(Ab + r * 128 + (((4 + kc) ^ (r & 7)) << 4));
    }
#pragma unroll
    for (int i = 0; i < 4; ++i) {
      int r = wr * 64 + i * 16 + lr;
      af[i] = *(const bf16x8*)(Ab + r * 128 + ((kc ^ (r & 7)) << 4));
    }
    __builtin_amdgcn_sched_barrier(0);
    stage(fslot, src);
    __builtin_amdgcn_sched_barrier(0);
    __builtin_amdgcn_s_setprio(1);
#pragma unroll
    for (int i = 0; i < 4; ++i)
#pragma unroll
      for (int j = 0; j < 4; ++j)
        acc[i][j] = __builtin_amdgcn_mfma_f32_16x16x32_bf16(af[i], bfr[j], acc[i][j], 0, 0, 0);
    __builtin_amdgcn_s_setprio(0);
    __builtin_amdgcn_sched_barrier(0);
    asm volatile("s_waitcnt vmcnt(4)" ::: "memory");
    __builtin_amdgcn_s_barrier();
    asm volatile("" ::: "memory");
  }
}

// ---- k_prep: 0-255 gmat 32x32 | 256-287 u | 288-319 wv2 | 320 consts | 321+ R->bf16 ----
__global__ __launch_bounds__(256) void k_prep(
    const float* __restrict__ R, const float* __restrict__ Wq, const float* __restrict__ Wk,
    const float* __restrict__ Wv, const float* __restrict__ bq, const float* __restrict__ bv,
    const float* __restrict__ W1, const float* __restrict__ b1,
    const float* __restrict__ W2, const float* __restrict__ b2,
    unsigned short* __restrict__ Gt, unsigned short* __restrict__ Rb16,
    float* __restrict__ u, float* __restrict__ wv2, float* __restrict__ consts) {
  __shared__ __align__(16) float As[16][34];
  __shared__ __align__(16) float Bs[16][34];
  __shared__ float vecs[512];
  __shared__ float red2[16][17];
  const int bid = blockIdx.x;
  const int t = threadIdx.x;

  if (bid >= 321) {  // R -> bf16 convert only
    size_t base = ((size_t)(bid - 321) * 256 + t) * 8;
    float4 r0 = *(const float4*)&R[base];
    float4 r1 = *(const float4*)&R[base + 4];
    ushort4 lo, hi;
    lo.x = f2bf(r0.x); lo.y = f2bf(r0.y); lo.z = f2bf(r0.z); lo.w = f2bf(r0.w);
    hi.x = f2bf(r1.x); hi.y = f2bf(r1.y); hi.z = f2bf(r1.z); hi.w = f2bf(r1.w);
    *(ushort4*)&Rb16[base] = lo;
    *(ushort4*)&Rb16[base + 4] = hi;
    return;
  }
  if (bid < 256) {  // Gt[q2][q1] = sum_d Wq[d][q1] Wk[d][q2], 32x32 tiles
    int tm = t & 15, tn = t >> 4;
    int q1b = (bid & 15) * 32, q2b = (bid >> 4) * 32;
    int lk = t >> 4, lc = (t & 15) * 2;
    float acc[2][2] = {};
    for (int kb = 0; kb < DIM; kb += 16) {
      *(float2*)&As[lk][lc] = *(const float2*)&Wq[(size_t)(kb + lk) * DIM + q1b + lc];
      *(float2*)&Bs[lk][lc] = *(const float2*)&Wk[(size_t)(kb + lk) * DIM + q2b + lc];
      __syncthreads();
#pragma unroll
      for (int k = 0; k < 16; ++k) {
        float a0 = As[k][tm * 2], a1 = As[k][tm * 2 + 1];
        float b0 = Bs[k][tn * 2], b1v = Bs[k][tn * 2 + 1];
        acc[0][0] = fmaf(a0, b0, acc[0][0]); acc[0][1] = fmaf(a0, b1v, acc[0][1]);
        acc[1][0] = fmaf(a1, b0, acc[1][0]); acc[1][1] = fmaf(a1, b1v, acc[1][1]);
      }
      __syncthreads();
    }
#pragma unroll
    for (int i = 0; i < 2; ++i)
#pragma unroll
      for (int j = 0; j < 2; ++j)
        Gt[(size_t)(q2b + tn * 2 + j) * DIM + (q1b + tm * 2 + i)] = f2bf(acc[i][j]);
    return;
  }
  if (bid < 320) {
    bool isU = bid < 288;
    int qb = (bid - (isU ? 256 : 288)) * 16;
    if (isU) {
      vecs[t] = bq[t];
      vecs[t + 256] = bq[t + 256];
    } else {
      for (int d = t; d < DIM; d += 256) {
        float s = 0.f;
        for (int j = 0; j < HID; ++j) s = fmaf(W2[j], W1[(size_t)j * DIM + d], s);
        vecs[d] = s;
      }
    }
    __syncthreads();
    const float* M = isU ? Wk : Wv;
    int ql = t & 15, ds = t >> 4;
    float s = 0.f;
#pragma unroll 8
    for (int i = 0; i < 32; ++i) {
      int d = ds * 32 + i;
      s = fmaf(vecs[d], M[(size_t)d * DIM + qb + ql], s);
    }
    red2[ds][ql] = s;
    __syncthreads();
    if (t < 16) {
      float r = 0.f;
#pragma unroll
      for (int k = 0; k < 16; ++k) r += red2[k][t];
      (isU ? u : wv2)[qb + t] = r;
    }
    return;
  }
  // bid == 320: const1 = bv.w12 ; c0 = W2.b1 + b2
  {
    for (int d = t; d < DIM; d += 256) {
      float s = 0.f;
      for (int j = 0; j < HID; ++j) s = fmaf(W2[j], W1[(size_t)j * DIM + d], s);
      vecs[d] = s;
    }
    __syncthreads();
    float* red = (float*)red2;
    red[t] = bv[t] * vecs[t] + bv[t + 256] * vecs[t + 256];
    __syncthreads();
    for (int o = 128; o > 0; o >>= 1) {
      if (t < o) red[t] += red[t + o];
      __syncthreads();
    }
    if (t == 0) {
      consts[0] = red[0];
      float s = b2[0];
      for (int j = 0; j < HID; ++j) s = fmaf(W2[j], b1[j], s);
      consts[1] = s;
    }
  }
}

// ---- k_projT: T = Rb16 @ Gt^T + u (128x128 core); blockIdx.y==0 also computes vw ----
__global__ __launch_bounds__(256, 2) void k_projT(const unsigned short* __restrict__ Rb16,
                                                  const unsigned short* __restrict__ Gt,
                                                  const float* __restrict__ u,
                                                  const float* __restrict__ wv2,
                                                  unsigned short* __restrict__ Tb16,
                                                  float* __restrict__ vw) {
  __shared__ __align__(16) char smem[49152];
  __shared__ float u_lds[128];
  int t = threadIdx.x;
  size_t rowb = (size_t)blockIdx.x * 128;
  int colb = blockIdx.y * 128;
  if (t < 128) u_lds[t] = u[colb + t];
  f32x4 acc[4][4] = {};
  gemm128_core(Rb16 + rowb * DIM, Gt + (size_t)colb * DIM, smem, acc);
  int lane = t & 63, w = t >> 6, wr = w >> 1, wc = w & 1;
  int lr = lane & 15, kq = lane >> 4;
#pragma unroll
  for (int i = 0; i < 4; ++i)
#pragma unroll
    for (int j = 0; j < 4; ++j)
#pragma unroll
      for (int r = 0; r < 4; ++r) {
        int row = wr * 64 + i * 16 + kq * 4 + r;
        int col = wc * 64 + j * 16 + lr;
        Tb16[(rowb + row) * DIM + colb + col] = f2bf(acc[i][j][r] + u_lds[col]);
      }
  if (blockIdx.y == 0) {  // vw[n] = Rb16[n].wv2 (const1 folded into k_final)
    float* wv2s = (float*)smem;  // reuse after all reads done
    __syncthreads();
    if (t < 256) { wv2s[t] = wv2[t]; wv2s[t + 256] = wv2[t + 256]; }
    __syncthreads();
    int row = (int)rowb + (t >> 1);
    const unsigned short* rp = Rb16 + (size_t)row * DIM + (t & 1) * 256;
    const float* wp = wv2s + (t & 1) * 256;
    float s = 0.f;
#pragma unroll 8
    for (int i = 0; i < 32; ++i) {
      bf16x8 v = *(const bf16x8*)(rp + i * 8);
#pragma unroll
      for (int e = 0; e < 8; ++e) s = fmaf(bf2f((unsigned short)v[e]), wp[i * 8 + e], s);
    }
    s += __shfl_xor(s, 1);
    if ((t & 1) == 0) vw[row] = s;
  }
}

// ---- k_qk: S = T @ R^T (256x256, 32x32x16 core) + exp + fused s1/den partials ----
__global__ __launch_bounds__(512, 2) void k_qk(const unsigned short* __restrict__ Tb16,
                                               const unsigned short* __restrict__ Rb16,
                                               const float* __restrict__ vw,
                                               float* __restrict__ part_s1,
                                               float* __restrict__ part_den) {
  __shared__ __align__(16) char smem[98304];
  __shared__ float vw_lds[256];
  __shared__ float red_s1[4][256], red_den[4][256];
  int t = threadIdx.x;
  // XCD swizzle: each XCD owns one batch (T+R panels fit its 4MB L2)
  int orig = blockIdx.x;
  int wgid = (orig & 7) * 64 + (orig >> 3);
  int b = wgid >> 6;
  int nb = ((wgid >> 3) & 7) * 256;
  int mb = (wgid & 7) * 256;
  if (t < 256) vw_lds[t] = vw[b * SEQ + mb + t];
  f32x16 acc[4][2] = {};
  gemm256_core32(Tb16 + ((size_t)b * SEQ + nb) * DIM,
                 Rb16 + ((size_t)b * SEQ + mb) * DIM, smem, acc);
  int lane = t & 63, w = t >> 6, wr = w >> 2, wc = w & 3;
  int lm = lane & 31, kh = lane >> 5;
  const float rs = 0.044194173824159216f;  // 1/sqrt(512)
  float vwl[2];
#pragma unroll
  for (int fj = 0; fj < 2; ++fj) vwl[fj] = vw_lds[wc * 64 + fj * 32 + lm];
#pragma unroll
  for (int fi = 0; fi < 4; ++fi) {
#pragma unroll
    for (int reg = 0; reg < 16; ++reg) {
      int rl = wr * 128 + fi * 32 + (reg & 3) + 8 * (reg >> 2) + 4 * kh;
      float e0 = __expf(acc[fi][0][reg] * rs);
      float e1 = __expf(acc[fi][1][reg] * rs);
      float sa = fmaf(e0, vwl[0], e1 * vwl[1]);
      float sd = e0 + e1;
#pragma unroll
      for (int m = 1; m < 32; m <<= 1) { sa += __shfl_xor(sa, m); sd += __shfl_xor(sd, m); }
      if (lm == 0) {
        red_s1[wc][rl] = sa;
        red_den[wc][rl] = sd;
      }
    }
  }
  __syncthreads();
  if (t < 256) {
    size_t o = ((size_t)b * 8 + (mb >> 8)) * SEQ + nb + t;
    part_s1[o] = red_s1[0][t] + red_s1[1][t] + red_s1[2][t] + red_s1[3][t];
    part_den[o] = red_den[0][t] + red_den[1][t] + red_den[2][t] + red_den[3][t];
  }
}

// ---- k_final: winner = s1/den + const1 + c0 ----
__global__ void k_final(const float* __restrict__ part_s1, const float* __restrict__ part_den,
                        const float* __restrict__ consts, float* __restrict__ out) {
  int n = blockIdx.x * 256 + threadIdx.x;
  int b = n >> 11, nn = n & 2047;
  float s1 = 0.f, dn = 0.f;
#pragma unroll
  for (int i = 0; i < 8; ++i) {
    size_t o = ((size_t)b * 8 + i) * SEQ + nn;
    s1 += part_s1[o];
    dn += part_den[o];
  }
  out[n] = s1 / dn + consts[0] + consts[1];
}

extern "C" void kernel_launch(void* const* d_in, const int* in_sizes, int n_in,
                              void* d_out, int out_size, void* d_ws, size_t ws_size,
                              hipStream_t stream) {
  const float* R  = (const float*)d_in[0];
  const float* Wq = (const float*)d_in[1];
  const float* bq = (const float*)d_in[2];
  const float* Wk = (const float*)d_in[3];
  const float* bk = (const float*)d_in[4];  // cancels in row-softmax
  const float* Wv = (const float*)d_in[5];
  const float* bv = (const float*)d_in[6];
  const float* W1 = (const float*)d_in[7];
  const float* b1 = (const float*)d_in[8];
  const float* W2 = (const float*)d_in[9];
  const float* b2 = (const float*)d_in[10];
  (void)bk;
  float* out = (float*)d_out;

  char* p = (char*)d_ws;
  unsigned short* Rb16 = (unsigned short*)p; p += (size_t)MTOT * DIM * 2;
  unsigned short* Tb16 = (unsigned short*)p; p += (size_t)MTOT * DIM * 2;
  unsigned short* Gt   = (unsigned short*)p; p += (size_t)DIM * DIM * 2;
  float* part_s1  = (float*)p; p += (size_t)BATCH * 8 * SEQ * 4;
  float* part_den = (float*)p; p += (size_t)BATCH * 8 * SEQ * 4;
  float* u      = (float*)p; p += DIM * 4;
  float* wv2    = (float*)p; p += DIM * 4;
  float* vw     = (float*)p; p += MTOT * 4;
  float* consts = (float*)p; p += 16;

  hipLaunchKernelGGL(k_prep, dim3(321 + MTOT * DIM / (256 * 8)), dim3(256), 0, stream,
                     R, Wq, Wk, Wv, bq, bv, W1, b1, W2, b2, Gt, Rb16, u, wv2, consts);
  hipLaunchKernelGGL(k_projT, dim3(MTOT / 128, DIM / 128), dim3(256), 0, stream,
                     Rb16, Gt, u, wv2, Tb16, vw);
  hipLaunchKernelGGL(k_qk, dim3(512), dim3(512), 0, stream, Tb16, Rb16, vw, part_s1, part_den);
  hipLaunchKernelGGL(k_final, dim3(MTOT / 256), dim3(256), 0, stream,
                     part_s1, part_den, consts, out);
}

// Round 12
// 97.638 us; speedup vs baseline: 3.6079x; 1.1716x over previous
//
#include <hip/hip_runtime.h>
#include <math.h>

#define BATCH 8
#define SEQ 2048
#define DIM 512
#define MTOT (BATCH*SEQ)
#define HID 30

typedef short bf16x8 __attribute__((ext_vector_type(8)));
typedef float f32x4 __attribute__((ext_vector_type(4)));

__device__ __forceinline__ unsigned short f2bf(float f) {
  unsigned int u = __float_as_uint(f);
  unsigned int r = (u + 0x7FFFu + ((u >> 16) & 1u)) >> 16;  // RNE
  return (unsigned short)r;
}
__device__ __forceinline__ float bf2f(unsigned short u) {
  return __uint_as_float((unsigned int)u << 16);
}

__device__ __forceinline__ void gload_lds16(const void* g, void* l) {
  __builtin_amdgcn_global_load_lds((const __attribute__((address_space(1))) void*)g,
                                   (__attribute__((address_space(3))) void*)l, 16, 0, 0);
}

// ---- 256x256 tile GEMM core: C = A * B^T, row-major [256][K=512] bf16.
// BK=32, 8 waves (2x4), 4-slot LDS ring, prefetch distance 3, counted vmcnt(8),
// ONE barrier per K-tile. (R7-verified structure, k_qk 46.8us; ring deepened 3->4
// so the end-of-tile wait retires loads issued TWO tiles earlier.)
// Zero-conflict macro-row layout (verified): row r = 8x16B chunks (A: ss0-3, B: ss4-7),
// physical slot = ss ^ (r&7); staged linearly via global_load_lds, pre-swizzled source.
// WAR safety: stage target slot (kt+3)&3 was last read at tile kt-1, whose reads were
// lgkm-consumed before that tile's MFMA, hence before its end barrier.
__device__ __forceinline__ void gemm256_core(const unsigned short* __restrict__ gA,
                                             const unsigned short* __restrict__ gB,
                                             char* smem, f32x4 (&acc)[8][4]) {
  const int t = threadIdx.x;
  const int lane = t & 63;
  const int w = t >> 6;
  const int wr = w >> 2, wc = w & 3;
  const int lr = lane & 15, kc = lane >> 4;
  const int ss = (t & 7) ^ ((t >> 3) & 7);
  const unsigned short* gsrc = (ss < 4 ? gA : gB) + (size_t)(t >> 3) * DIM + (ss & 3) * 8;
  const uint32_t dbase = (uint32_t)(t & 448) * 16;  // wave-uniform base; HW adds lane*16

  auto stage = [&](int slot, int kt) {
#pragma unroll
    for (int q = 0; q < 4; ++q)
      gload_lds16(gsrc + (size_t)(q * 64) * DIM + kt * 32,
                  smem + slot * 32768 + q * 8192 + dbase);
  };

  stage(0, 0); stage(1, 1); stage(2, 2);
  asm volatile("s_waitcnt vmcnt(8)" ::: "memory");
  __builtin_amdgcn_s_barrier();
  asm volatile("" ::: "memory");

#pragma unroll
  for (int kt = 0; kt < 16; ++kt) {
    const char* Ab = smem + (kt & 3) * 32768;
    const int fslot = (kt + 3) & 3;
    const int src = (kt + 3 < 16) ? (kt + 3) : 15;  // dummy tail keeps vmcnt uniform
    bf16x8 bfr[4], af[4], af2[4];
#pragma unroll
    for (int j = 0; j < 4; ++j) {
      int r = wc * 64 + j * 16 + lr;
      bfr[j] = *(const bf16x8*)(Ab + r * 128 + (((4 + kc) ^ (r & 7)) << 4));
    }
#pragma unroll
    for (int i = 0; i < 4; ++i) {
      int r = wr * 128 + i * 16 + lr;
      af[i] = *(const bf16x8*)(Ab + r * 128 + ((kc ^ (r & 7)) << 4));
    }
    __builtin_amdgcn_sched_barrier(0);
#pragma unroll
    for (int i = 0; i < 4; ++i) {
      int r = wr * 128 + (i + 4) * 16 + lr;
      af2[i] = *(const bf16x8*)(Ab + r * 128 + ((kc ^ (r & 7)) << 4));
    }
    __builtin_amdgcn_sched_barrier(0);
    stage(fslot, src);
    __builtin_amdgcn_sched_barrier(0);
    __builtin_amdgcn_s_setprio(1);
#pragma unroll
    for (int i = 0; i < 4; ++i)   // compiler emits lgkmcnt(4): af2 still in flight
#pragma unroll
      for (int j = 0; j < 4; ++j)
        acc[i][j] = __builtin_amdgcn_mfma_f32_16x16x32_bf16(af[i], bfr[j], acc[i][j], 0, 0, 0);
    __builtin_amdgcn_s_setprio(0);
    __builtin_amdgcn_sched_barrier(0);
    __builtin_amdgcn_s_setprio(1);
#pragma unroll
    for (int i = 0; i < 4; ++i)   // compiler emits lgkmcnt(0)
#pragma unroll
      for (int j = 0; j < 4; ++j)
        acc[i + 4][j] = __builtin_amdgcn_mfma_f32_16x16x32_bf16(af2[i], bfr[j], acc[i + 4][j], 0, 0, 0);
    __builtin_amdgcn_s_setprio(0);
    __builtin_amdgcn_sched_barrier(0);
    asm volatile("s_waitcnt vmcnt(8)" ::: "memory");  // tile kt+1 (issued @ kt-2) landed
    __builtin_amdgcn_s_barrier();
    asm volatile("" ::: "memory");
  }
}

// ---- 128x128 tile core: 4 waves (2x2), BK=32, 4-slot ring (16KB/slot), 1 barrier/tile. ----
__device__ __forceinline__ void gemm128_core(const unsigned short* __restrict__ gA,
                                             const unsigned short* __restrict__ gB,
                                             char* smem, f32x4 (&acc)[4][4]) {
  const int t = threadIdx.x;  // 0..255
  const int lane = t & 63;
  const int w = t >> 6;
  const int wr = w >> 1, wc = w & 1;
  const int lr = lane & 15, kc = lane >> 4;
  const int ss = (t & 7) ^ ((t >> 3) & 7);
  const unsigned short* gsrc = (ss < 4 ? gA : gB) + (size_t)(t >> 3) * DIM + (ss & 3) * 8;
  const uint32_t dbase = (uint32_t)(t & 192) * 16;

  auto stage = [&](int slot, int kt) {
#pragma unroll
    for (int q = 0; q < 4; ++q)
      gload_lds16(gsrc + (size_t)(q * 32) * DIM + kt * 32,
                  smem + slot * 16384 + q * 4096 + dbase);
  };

  stage(0, 0); stage(1, 1); stage(2, 2);
  asm volatile("s_waitcnt vmcnt(8)" ::: "memory");
  __builtin_amdgcn_s_barrier();
  asm volatile("" ::: "memory");

#pragma unroll
  for (int kt = 0; kt < 16; ++kt) {
    const char* Ab = smem + (kt & 3) * 16384;
    const int fslot = (kt + 3) & 3;
    const int src = (kt + 3 < 16) ? (kt + 3) : 15;
    bf16x8 bfr[4], af[4];
#pragma unroll
    for (int j = 0; j < 4; ++j) {
      int r = wc * 64 + j * 16 + lr;
      bfr[j] = *(const bf16x8*)(Ab + r * 128 + (((4 + kc) ^ (r & 7)) << 4));
    }
#pragma unroll
    for (int i = 0; i < 4; ++i) {
      int r = wr * 64 + i * 16 + lr;
      af[i] = *(const bf16x8*)(Ab + r * 128 + ((kc ^ (r & 7)) << 4));
    }
    __builtin_amdgcn_sched_barrier(0);
    stage(fslot, src);
    __builtin_amdgcn_sched_barrier(0);
    __builtin_amdgcn_s_setprio(1);
#pragma unroll
    for (int i = 0; i < 4; ++i)
#pragma unroll
      for (int j = 0; j < 4; ++j)
        acc[i][j] = __builtin_amdgcn_mfma_f32_16x16x32_bf16(af[i], bfr[j], acc[i][j], 0, 0, 0);
    __builtin_amdgcn_s_setprio(0);
    __builtin_amdgcn_sched_barrier(0);
    asm volatile("s_waitcnt vmcnt(8)" ::: "memory");
    __builtin_amdgcn_s_barrier();
    asm volatile("" ::: "memory");
  }
}

// ---- k_prep: 0-255 gmat 32x32 | 256-287 u | 288-319 wv2 | 320 consts | 321+ R->bf16 ----
__global__ __launch_bounds__(256) void k_prep(
    const float* __restrict__ R, const float* __restrict__ Wq, const float* __restrict__ Wk,
    const float* __restrict__ Wv, const float* __restrict__ bq, const float* __restrict__ bv,
    const float* __restrict__ W1, const float* __restrict__ b1,
    const float* __restrict__ W2, const float* __restrict__ b2,
    unsigned short* __restrict__ Gt, unsigned short* __restrict__ Rb16,
    float* __restrict__ u, float* __restrict__ wv2, float* __restrict__ consts) {
  __shared__ __align__(16) float As[16][34];
  __shared__ __align__(16) float Bs[16][34];
  __shared__ float vecs[512];
  __shared__ float red2[16][17];
  const int bid = blockIdx.x;
  const int t = threadIdx.x;

  if (bid >= 321) {  // R -> bf16 convert only
    size_t base = ((size_t)(bid - 321) * 256 + t) * 8;
    float4 r0 = *(const float4*)&R[base];
    float4 r1 = *(const float4*)&R[base + 4];
    ushort4 lo, hi;
    lo.x = f2bf(r0.x); lo.y = f2bf(r0.y); lo.z = f2bf(r0.z); lo.w = f2bf(r0.w);
    hi.x = f2bf(r1.x); hi.y = f2bf(r1.y); hi.z = f2bf(r1.z); hi.w = f2bf(r1.w);
    *(ushort4*)&Rb16[base] = lo;
    *(ushort4*)&Rb16[base + 4] = hi;
    return;
  }
  if (bid < 256) {  // Gt[q2][q1] = sum_d Wq[d][q1] Wk[d][q2], 32x32 tiles
    int tm = t & 15, tn = t >> 4;
    int q1b = (bid & 15) * 32, q2b = (bid >> 4) * 32;
    int lk = t >> 4, lc = (t & 15) * 2;
    float acc[2][2] = {};
    for (int kb = 0; kb < DIM; kb += 16) {
      *(float2*)&As[lk][lc] = *(const float2*)&Wq[(size_t)(kb + lk) * DIM + q1b + lc];
      *(float2*)&Bs[lk][lc] = *(const float2*)&Wk[(size_t)(kb + lk) * DIM + q2b + lc];
      __syncthreads();
#pragma unroll
      for (int k = 0; k < 16; ++k) {
        float a0 = As[k][tm * 2], a1 = As[k][tm * 2 + 1];
        float b0 = Bs[k][tn * 2], b1v = Bs[k][tn * 2 + 1];
        acc[0][0] = fmaf(a0, b0, acc[0][0]); acc[0][1] = fmaf(a0, b1v, acc[0][1]);
        acc[1][0] = fmaf(a1, b0, acc[1][0]); acc[1][1] = fmaf(a1, b1v, acc[1][1]);
      }
      __syncthreads();
    }
#pragma unroll
    for (int i = 0; i < 2; ++i)
#pragma unroll
      for (int j = 0; j < 2; ++j)
        Gt[(size_t)(q2b + tn * 2 + j) * DIM + (q1b + tm * 2 + i)] = f2bf(acc[i][j]);
    return;
  }
  if (bid < 320) {
    bool isU = bid < 288;
    int qb = (bid - (isU ? 256 : 288)) * 16;
    if (isU) {
      vecs[t] = bq[t];
      vecs[t + 256] = bq[t + 256];
    } else {
      for (int d = t; d < DIM; d += 256) {
        float s = 0.f;
        for (int j = 0; j < HID; ++j) s = fmaf(W2[j], W1[(size_t)j * DIM + d], s);
        vecs[d] = s;
      }
    }
    __syncthreads();
    const float* M = isU ? Wk : Wv;
    int ql = t & 15, ds = t >> 4;
    float s = 0.f;
#pragma unroll 8
    for (int i = 0; i < 32; ++i) {
      int d = ds * 32 + i;
      s = fmaf(vecs[d], M[(size_t)d * DIM + qb + ql], s);
    }
    red2[ds][ql] = s;
    __syncthreads();
    if (t < 16) {
      float r = 0.f;
#pragma unroll
      for (int k = 0; k < 16; ++k) r += red2[k][t];
      (isU ? u : wv2)[qb + t] = r;
    }
    return;
  }
  // bid == 320: const1 = bv.w12 ; c0 = W2.b1 + b2
  {
    for (int d = t; d < DIM; d += 256) {
      float s = 0.f;
      for (int j = 0; j < HID; ++j) s = fmaf(W2[j], W1[(size_t)j * DIM + d], s);
      vecs[d] = s;
    }
    __syncthreads();
    float* red = (float*)red2;
    red[t] = bv[t] * vecs[t] + bv[t + 256] * vecs[t + 256];
    __syncthreads();
    for (int o = 128; o > 0; o >>= 1) {
      if (t < o) red[t] += red[t + o];
      __syncthreads();
    }
    if (t == 0) {
      consts[0] = red[0];
      float s = b2[0];
      for (int j = 0; j < HID; ++j) s = fmaf(W2[j], b1[j], s);
      consts[1] = s;
    }
  }
}

// ---- k_projT: T = Rb16 @ Gt^T + u (128x128 core); blockIdx.y==0 also computes vw ----
__global__ __launch_bounds__(256, 2) void k_projT(const unsigned short* __restrict__ Rb16,
                                                  const unsigned short* __restrict__ Gt,
                                                  const float* __restrict__ u,
                                                  const float* __restrict__ wv2,
                                                  unsigned short* __restrict__ Tb16,
                                                  float* __restrict__ vw) {
  __shared__ __align__(16) char smem[65536];
  __shared__ float u_lds[128];
  int t = threadIdx.x;
  size_t rowb = (size_t)blockIdx.x * 128;
  int colb = blockIdx.y * 128;
  if (t < 128) u_lds[t] = u[colb + t];
  f32x4 acc[4][4] = {};
  gemm128_core(Rb16 + rowb * DIM, Gt + (size_t)colb * DIM, smem, acc);
  int lane = t & 63, w = t >> 6, wr = w >> 1, wc = w & 1;
  int lr = lane & 15, kq = lane >> 4;
#pragma unroll
  for (int i = 0; i < 4; ++i)
#pragma unroll
    for (int j = 0; j < 4; ++j)
#pragma unroll
      for (int r = 0; r < 4; ++r) {
        int row = wr * 64 + i * 16 + kq * 4 + r;
        int col = wc * 64 + j * 16 + lr;
        Tb16[(rowb + row) * DIM + colb + col] = f2bf(acc[i][j][r] + u_lds[col]);
      }
  if (blockIdx.y == 0) {  // vw[n] = Rb16[n].wv2 (const1 folded into k_final)
    // slot-0 reuse is safe: the kt=15 vmcnt(8) retired the kt=13 (slot-0) dummy writes;
    // loads still in flight at exit target slots 1,2 only.
    float* wv2s = (float*)smem;
    __syncthreads();
    if (t < 256) { wv2s[t] = wv2[t]; wv2s[t + 256] = wv2[t + 256]; }
    __syncthreads();
    int row = (int)rowb + (t >> 1);
    const unsigned short* rp = Rb16 + (size_t)row * DIM + (t & 1) * 256;
    const float* wp = wv2s + (t & 1) * 256;
    float s = 0.f;
#pragma unroll 8
    for (int i = 0; i < 32; ++i) {
      bf16x8 v = *(const bf16x8*)(rp + i * 8);
#pragma unroll
      for (int e = 0; e < 8; ++e) s = fmaf(bf2f((unsigned short)v[e]), wp[i * 8 + e], s);
    }
    s += __shfl_xor(s, 1);
    if ((t & 1) == 0) vw[row] = s;
  }
}

// ---- k_qk: S = T @ R^T (256x256 core) + exp + fused s1/den partials ----
__global__ __launch_bounds__(512, 2) void k_qk(const unsigned short* __restrict__ Tb16,
                                               const unsigned short* __restrict__ Rb16,
                                               const float* __restrict__ vw,
                                               float* __restrict__ part_s1,
                                               float* __restrict__ part_den) {
  __shared__ __align__(16) char smem[131072];
  __shared__ float vw_lds[256];
  __shared__ float red_s1[4][256], red_den[4][256];
  int t = threadIdx.x;
  // XCD swizzle: each XCD owns one batch (T+R panels fit its 4MB L2)
  int orig = blockIdx.x;
  int wgid = (orig & 7) * 64 + (orig >> 3);
  int b = wgid >> 6;
  int nb = ((wgid >> 3) & 7) * 256;
  int mb = (wgid & 7) * 256;
  if (t < 256) vw_lds[t] = vw[b * SEQ + mb + t];
  f32x4 acc[8][4] = {};
  gemm256_core(Tb16 + ((size_t)b * SEQ + nb) * DIM,
               Rb16 + ((size_t)b * SEQ + mb) * DIM, smem, acc);
  int lane = t & 63, w = t >> 6, wr = w >> 2, wc = w & 3;
  int lr = lane & 15, kq = lane >> 4;
  const float rs = 0.044194173824159216f;  // 1/sqrt(512)
  float vwl[4];
#pragma unroll
  for (int j = 0; j < 4; ++j) vwl[j] = vw_lds[wc * 64 + j * 16 + lr];
#pragma unroll
  for (int i = 0; i < 8; ++i) {
#pragma unroll
    for (int r = 0; r < 4; ++r) {
      float sa = 0.f, sd = 0.f;
#pragma unroll
      for (int j = 0; j < 4; ++j) {
        float e = __expf(acc[i][j][r] * rs);
        sa = fmaf(e, vwl[j], sa);
        sd += e;
      }
#pragma unroll
      for (int m = 1; m < 16; m <<= 1) { sa += __shfl_xor(sa, m); sd += __shfl_xor(sd, m); }
      if (lr == 0) {
        int rl = wr * 128 + i * 16 + kq * 4 + r;
        red_s1[wc][rl] = sa;
        red_den[wc][rl] = sd;
      }
    }
  }
  __syncthreads();
  if (t < 256) {
    size_t o = ((size_t)b * 8 + (mb >> 8)) * SEQ + nb + t;
    part_s1[o] = red_s1[0][t] + red_s1[1][t] + red_s1[2][t] + red_s1[3][t];
    part_den[o] = red_den[0][t] + red_den[1][t] + red_den[2][t] + red_den[3][t];
  }
}

// ---- k_final: winner = s1/den + const1 + c0 ----
__global__ void k_final(const float* __restrict__ part_s1, const float* __restrict__ part_den,
                        const float* __restrict__ consts, float* __restrict__ out) {
  int n = blockIdx.x * 256 + threadIdx.x;
  int b = n >> 11, nn = n & 2047;
  float s1 = 0.f, dn = 0.f;
#pragma unroll
  for (int i = 0; i < 8; ++i) {
    size_t o = ((size_t)b * 8 + i) * SEQ + nn;
    s1 += part_s1[o];
    dn += part_den[o];
  }
  out[n] = s1 / dn + consts[0] + consts[1];
}

extern "C" void kernel_launch(void* const* d_in, const int* in_sizes, int n_in,
                              void* d_out, int out_size, void* d_ws, size_t ws_size,
                              hipStream_t stream) {
  const float* R  = (const float*)d_in[0];
  const float* Wq = (const float*)d_in[1];
  const float* bq = (const float*)d_in[2];
  const float* Wk = (const float*)d_in[3];
  const float* bk = (const float*)d_in[4];  // cancels in row-softmax
  const float* Wv = (const float*)d_in[5];
  const float* bv = (const float*)d_in[6];
  const float* W1 = (const float*)d_in[7];
  const float* b1 = (const float*)d_in[8];
  const float* W2 = (const float*)d_in[9];
  const float* b2 = (const float*)d_in[10];
  (void)bk;
  float* out = (float*)d_out;

  char* p = (char*)d_ws;
  unsigned short* Rb16 = (unsigned short*)p; p += (size_t)MTOT * DIM * 2;
  unsigned short* Tb16 = (unsigned short*)p; p += (size_t)MTOT * DIM * 2;
  unsigned short* Gt   = (unsigned short*)p; p += (size_t)DIM * DIM * 2;
  float* part_s1  = (float*)p; p += (size_t)BATCH * 8 * SEQ * 4;
  float* part_den = (float*)p; p += (size_t)BATCH * 8 * SEQ * 4;
  float* u      = (float*)p; p += DIM * 4;
  float* wv2    = (float*)p; p += DIM * 4;
  float* vw     = (float*)p; p += MTOT * 4;
  float* consts = (float*)p; p += 16;

  hipLaunchKernelGGL(k_prep, dim3(321 + MTOT * DIM / (256 * 8)), dim3(256), 0, stream,
                     R, Wq, Wk, Wv, bq, bv, W1, b1, W2, b2, Gt, Rb16, u, wv2, consts);
  hipLaunchKernelGGL(k_projT, dim3(MTOT / 128, DIM / 128), dim3(256), 0, stream,
                     Rb16, Gt, u, wv2, Tb16, vw);
  hipLaunchKernelGGL(k_qk, dim3(512), dim3(512), 0, stream, Tb16, Rb16, vw, part_s1, part_den);
  hipLaunchKernelGGL(k_final, dim3(MTOT / 256), dim3(256), 0, stream,
                     part_s1, part_den, consts, out);
}

// Round 13
// 95.025 us; speedup vs baseline: 3.7071x; 1.0275x over previous
//
#include <hip/hip_runtime.h>
#include <math.h>

#define BATCH 8
#define SEQ 2048
#define DIM 512
#define MTOT (BATCH*SEQ)
#define HID 30

typedef short bf16x8 __attribute__((ext_vector_type(8)));
typedef float f32x4 __attribute__((ext_vector_type(4)));

__device__ __forceinline__ unsigned short f2bf(float f) {
  unsigned int u = __float_as_uint(f);
  unsigned int r = (u + 0x7FFFu + ((u >> 16) & 1u)) >> 16;  // RNE
  return (unsigned short)r;
}
__device__ __forceinline__ float bf2f(unsigned short u) {
  return __uint_as_float((unsigned int)u << 16);
}

__device__ __forceinline__ void gload_lds16(const void* g, void* l) {
  __builtin_amdgcn_global_load_lds((const __attribute__((address_space(1))) void*)g,
                                   (__attribute__((address_space(3))) void*)l, 16, 0, 0);
}

// ---- 256x256 tile GEMM core, BK=64: C = A * B^T, row-major [256][K=512] bf16.
// 8 K-tiles of 64 (vs 16 of 32): HALF the barriers/waits -> half the per-tile sync tax,
// identical total LDS/MFMA work. 2-slot ring (2 x 64KB). stage(kt+1) issues at tile TOP,
// so the end-of-tile vmcnt(0) retires ~2600-cycle-old loads (not a hot drain).
// Layout: A and B in separate 32KB regions; each region = 256 macro-rows x 128B
// (8 chunks of 16B covering k 0..63), physical chunk = ss ^ (row&7) — the verified
// zero-conflict geometry (16-lane b128 read groups: fixed chunk, rows 0..15 -> 2 lanes/slot).
// Staging: per-region 4 gload_lds/thread, linear dest, pre-swizzled per-lane source
// (row_i = i*64 + (t>>3); ss = (t&7)^((t>>3)&7), independent of i since i*64 % 8 == 0).
// WAR (2-slot): stage(kt+1) targets slot of kt-1, whose reads finished before kt-1's
// end barrier.
__device__ __forceinline__ void gemm256_core(const unsigned short* __restrict__ gA,
                                             const unsigned short* __restrict__ gB,
                                             char* smem, f32x4 (&acc)[8][4]) {
  const int t = threadIdx.x;
  const int lane = t & 63;
  const int w = t >> 6;
  const int wr = w >> 2, wc = w & 3;
  const int lr = lane & 15, kc = lane >> 4;  // kc in 0..3: k-chunk within a kstep
  const int ss = (t & 7) ^ ((t >> 3) & 7);
  const size_t srcoff = (size_t)(t >> 3) * DIM + ss * 8;
  const uint32_t dbase = (uint32_t)(t & 448) * 16;  // wave-uniform; HW adds lane*16

  auto stage = [&](int kt) {
    char* slot = smem + (kt & 1) * 65536;
#pragma unroll
    for (int q = 0; q < 4; ++q) {
      gload_lds16(gA + srcoff + (size_t)(q * 64) * DIM + kt * 64, slot + q * 8192 + dbase);
      gload_lds16(gB + srcoff + (size_t)(q * 64) * DIM + kt * 64, slot + 32768 + q * 8192 + dbase);
    }
  };

  stage(0);
  asm volatile("s_waitcnt vmcnt(0)" ::: "memory");
  __builtin_amdgcn_s_barrier();
  asm volatile("" ::: "memory");

#pragma unroll
  for (int kt = 0; kt < 8; ++kt) {
    const char* Ab = smem + (kt & 1) * 65536;
    const char* Bb = Ab + 32768;
    if (kt < 7) stage(kt + 1);
    __builtin_amdgcn_sched_barrier(0);
#pragma unroll
    for (int s = 0; s < 2; ++s) {  // kstep: k-half of the 64-K tile
      bf16x8 bfr[4], af[4], af2[4];
      const int ch = s * 4 + kc;   // chunk 0..7
#pragma unroll
      for (int j = 0; j < 4; ++j) {
        int r = wc * 64 + j * 16 + lr;
        bfr[j] = *(const bf16x8*)(Bb + r * 128 + ((ch ^ (r & 7)) << 4));
      }
#pragma unroll
      for (int i = 0; i < 4; ++i) {
        int r = wr * 128 + i * 16 + lr;
        af[i] = *(const bf16x8*)(Ab + r * 128 + ((ch ^ (r & 7)) << 4));
      }
      __builtin_amdgcn_sched_barrier(0);
#pragma unroll
      for (int i = 0; i < 4; ++i) {
        int r = wr * 128 + (i + 4) * 16 + lr;
        af2[i] = *(const bf16x8*)(Ab + r * 128 + ((ch ^ (r & 7)) << 4));
      }
      __builtin_amdgcn_sched_barrier(0);
      __builtin_amdgcn_s_setprio(1);
#pragma unroll
      for (int i = 0; i < 4; ++i)   // compiler emits lgkmcnt(4): af2 still in flight
#pragma unroll
        for (int j = 0; j < 4; ++j)
          acc[i][j] = __builtin_amdgcn_mfma_f32_16x16x32_bf16(af[i], bfr[j], acc[i][j], 0, 0, 0);
      __builtin_amdgcn_s_setprio(0);
      __builtin_amdgcn_sched_barrier(0);
      __builtin_amdgcn_s_setprio(1);
#pragma unroll
      for (int i = 0; i < 4; ++i)   // lgkmcnt(0)
#pragma unroll
        for (int j = 0; j < 4; ++j)
          acc[i + 4][j] = __builtin_amdgcn_mfma_f32_16x16x32_bf16(af2[i], bfr[j], acc[i + 4][j], 0, 0, 0);
      __builtin_amdgcn_s_setprio(0);
      __builtin_amdgcn_sched_barrier(0);
    }
    asm volatile("s_waitcnt vmcnt(0)" ::: "memory");  // kt+1's loads issued at tile top
    __builtin_amdgcn_s_barrier();
    asm volatile("" ::: "memory");
  }
}

// ---- 128x128 tile core: 4 waves (2x2), BK=32, 4-slot ring, 1 barrier/tile (R12). ----
__device__ __forceinline__ void gemm128_core(const unsigned short* __restrict__ gA,
                                             const unsigned short* __restrict__ gB,
                                             char* smem, f32x4 (&acc)[4][4]) {
  const int t = threadIdx.x;  // 0..255
  const int lane = t & 63;
  const int w = t >> 6;
  const int wr = w >> 1, wc = w & 1;
  const int lr = lane & 15, kc = lane >> 4;
  const int ss = (t & 7) ^ ((t >> 3) & 7);
  const unsigned short* gsrc = (ss < 4 ? gA : gB) + (size_t)(t >> 3) * DIM + (ss & 3) * 8;
  const uint32_t dbase = (uint32_t)(t & 192) * 16;

  auto stage = [&](int slot, int kt) {
#pragma unroll
    for (int q = 0; q < 4; ++q)
      gload_lds16(gsrc + (size_t)(q * 32) * DIM + kt * 32,
                  smem + slot * 16384 + q * 4096 + dbase);
  };

  stage(0, 0); stage(1, 1); stage(2, 2);
  asm volatile("s_waitcnt vmcnt(8)" ::: "memory");
  __builtin_amdgcn_s_barrier();
  asm volatile("" ::: "memory");

#pragma unroll
  for (int kt = 0; kt < 16; ++kt) {
    const char* Ab = smem + (kt & 3) * 16384;
    const int fslot = (kt + 3) & 3;
    const int src = (kt + 3 < 16) ? (kt + 3) : 15;
    bf16x8 bfr[4], af[4];
#pragma unroll
    for (int j = 0; j < 4; ++j) {
      int r = wc * 64 + j * 16 + lr;
      bfr[j] = *(const bf16x8*)(Ab + r * 128 + (((4 + kc) ^ (r & 7)) << 4));
    }
#pragma unroll
    for (int i = 0; i < 4; ++i) {
      int r = wr * 64 + i * 16 + lr;
      af[i] = *(const bf16x8*)(Ab + r * 128 + ((kc ^ (r & 7)) << 4));
    }
    __builtin_amdgcn_sched_barrier(0);
    stage(fslot, src);
    __builtin_amdgcn_sched_barrier(0);
    __builtin_amdgcn_s_setprio(1);
#pragma unroll
    for (int i = 0; i < 4; ++i)
#pragma unroll
      for (int j = 0; j < 4; ++j)
        acc[i][j] = __builtin_amdgcn_mfma_f32_16x16x32_bf16(af[i], bfr[j], acc[i][j], 0, 0, 0);
    __builtin_amdgcn_s_setprio(0);
    __builtin_amdgcn_sched_barrier(0);
    asm volatile("s_waitcnt vmcnt(8)" ::: "memory");
    __builtin_amdgcn_s_barrier();
    asm volatile("" ::: "memory");
  }
}

// ---- k_prep: 0-255 gmat 32x32 | 256-287 u | 288-319 wv2 | 320 consts | 321+ R->bf16 ----
__global__ __launch_bounds__(256) void k_prep(
    const float* __restrict__ R, const float* __restrict__ Wq, const float* __restrict__ Wk,
    const float* __restrict__ Wv, const float* __restrict__ bq, const float* __restrict__ bv,
    const float* __restrict__ W1, const float* __restrict__ b1,
    const float* __restrict__ W2, const float* __restrict__ b2,
    unsigned short* __restrict__ Gt, unsigned short* __restrict__ Rb16,
    float* __restrict__ u, float* __restrict__ wv2, float* __restrict__ consts) {
  __shared__ __align__(16) float As[16][34];
  __shared__ __align__(16) float Bs[16][34];
  __shared__ float vecs[512];
  __shared__ float red2[16][17];
  const int bid = blockIdx.x;
  const int t = threadIdx.x;

  if (bid >= 321) {  // R -> bf16 convert only
    size_t base = ((size_t)(bid - 321) * 256 + t) * 8;
    float4 r0 = *(const float4*)&R[base];
    float4 r1 = *(const float4*)&R[base + 4];
    ushort4 lo, hi;
    lo.x = f2bf(r0.x); lo.y = f2bf(r0.y); lo.z = f2bf(r0.z); lo.w = f2bf(r0.w);
    hi.x = f2bf(r1.x); hi.y = f2bf(r1.y); hi.z = f2bf(r1.z); hi.w = f2bf(r1.w);
    *(ushort4*)&Rb16[base] = lo;
    *(ushort4*)&Rb16[base + 4] = hi;
    return;
  }
  if (bid < 256) {  // Gt[q2][q1] = sum_d Wq[d][q1] Wk[d][q2], 32x32 tiles
    int tm = t & 15, tn = t >> 4;
    int q1b = (bid & 15) * 32, q2b = (bid >> 4) * 32;
    int lk = t >> 4, lc = (t & 15) * 2;
    float acc[2][2] = {};
    for (int kb = 0; kb < DIM; kb += 16) {
      *(float2*)&As[lk][lc] = *(const float2*)&Wq[(size_t)(kb + lk) * DIM + q1b + lc];
      *(float2*)&Bs[lk][lc] = *(const float2*)&Wk[(size_t)(kb + lk) * DIM + q2b + lc];
      __syncthreads();
#pragma unroll
      for (int k = 0; k < 16; ++k) {
        float a0 = As[k][tm * 2], a1 = As[k][tm * 2 + 1];
        float b0 = Bs[k][tn * 2], b1v = Bs[k][tn * 2 + 1];
        acc[0][0] = fmaf(a0, b0, acc[0][0]); acc[0][1] = fmaf(a0, b1v, acc[0][1]);
        acc[1][0] = fmaf(a1, b0, acc[1][0]); acc[1][1] = fmaf(a1, b1v, acc[1][1]);
      }
      __syncthreads();
    }
#pragma unroll
    for (int i = 0; i < 2; ++i)
#pragma unroll
      for (int j = 0; j < 2; ++j)
        Gt[(size_t)(q2b + tn * 2 + j) * DIM + (q1b + tm * 2 + i)] = f2bf(acc[i][j]);
    return;
  }
  if (bid < 320) {
    bool isU = bid < 288;
    int qb = (bid - (isU ? 256 : 288)) * 16;
    if (isU) {
      vecs[t] = bq[t];
      vecs[t + 256] = bq[t + 256];
    } else {
      for (int d = t; d < DIM; d += 256) {
        float s = 0.f;
        for (int j = 0; j < HID; ++j) s = fmaf(W2[j], W1[(size_t)j * DIM + d], s);
        vecs[d] = s;
      }
    }
    __syncthreads();
    const float* M = isU ? Wk : Wv;
    int ql = t & 15, ds = t >> 4;
    float s = 0.f;
#pragma unroll 8
    for (int i = 0; i < 32; ++i) {
      int d = ds * 32 + i;
      s = fmaf(vecs[d], M[(size_t)d * DIM + qb + ql], s);
    }
    red2[ds][ql] = s;
    __syncthreads();
    if (t < 16) {
      float r = 0.f;
#pragma unroll
      for (int k = 0; k < 16; ++k) r += red2[k][t];
      (isU ? u : wv2)[qb + t] = r;
    }
    return;
  }
  // bid == 320: const1 = bv.w12 ; c0 = W2.b1 + b2
  {
    for (int d = t; d < DIM; d += 256) {
      float s = 0.f;
      for (int j = 0; j < HID; ++j) s = fmaf(W2[j], W1[(size_t)j * DIM + d], s);
      vecs[d] = s;
    }
    __syncthreads();
    float* red = (float*)red2;
    red[t] = bv[t] * vecs[t] + bv[t + 256] * vecs[t + 256];
    __syncthreads();
    for (int o = 128; o > 0; o >>= 1) {
      if (t < o) red[t] += red[t + o];
      __syncthreads();
    }
    if (t == 0) {
      consts[0] = red[0];
      float s = b2[0];
      for (int j = 0; j < HID; ++j) s = fmaf(W2[j], b1[j], s);
      consts[1] = s;
    }
  }
}

// ---- k_projT: T = Rb16 @ Gt^T + u (128x128 core); blockIdx.y==0 also computes vw ----
__global__ __launch_bounds__(256, 2) void k_projT(const unsigned short* __restrict__ Rb16,
                                                  const unsigned short* __restrict__ Gt,
                                                  const float* __restrict__ u,
                                                  const float* __restrict__ wv2,
                                                  unsigned short* __restrict__ Tb16,
                                                  float* __restrict__ vw) {
  __shared__ __align__(16) char smem[65536];
  __shared__ float u_lds[128];
  int t = threadIdx.x;
  size_t rowb = (size_t)blockIdx.x * 128;
  int colb = blockIdx.y * 128;
  if (t < 128) u_lds[t] = u[colb + t];
  f32x4 acc[4][4] = {};
  gemm128_core(Rb16 + rowb * DIM, Gt + (size_t)colb * DIM, smem, acc);
  int lane = t & 63, w = t >> 6, wr = w >> 1, wc = w & 1;
  int lr = lane & 15, kq = lane >> 4;
#pragma unroll
  for (int i = 0; i < 4; ++i)
#pragma unroll
    for (int j = 0; j < 4; ++j)
#pragma unroll
      for (int r = 0; r < 4; ++r) {
        int row = wr * 64 + i * 16 + kq * 4 + r;
        int col = wc * 64 + j * 16 + lr;
        Tb16[(rowb + row) * DIM + colb + col] = f2bf(acc[i][j][r] + u_lds[col]);
      }
  if (blockIdx.y == 0) {  // vw[n] = Rb16[n].wv2 (const1 folded into k_final)
    float* wv2s = (float*)smem;
    __syncthreads();
    if (t < 256) { wv2s[t] = wv2[t]; wv2s[t + 256] = wv2[t + 256]; }
    __syncthreads();
    int row = (int)rowb + (t >> 1);
    const unsigned short* rp = Rb16 + (size_t)row * DIM + (t & 1) * 256;
    const float* wp = wv2s + (t & 1) * 256;
    float s = 0.f;
#pragma unroll 8
    for (int i = 0; i < 32; ++i) {
      bf16x8 v = *(const bf16x8*)(rp + i * 8);
#pragma unroll
      for (int e = 0; e < 8; ++e) s = fmaf(bf2f((unsigned short)v[e]), wp[i * 8 + e], s);
    }
    s += __shfl_xor(s, 1);
    if ((t & 1) == 0) vw[row] = s;
  }
}

// ---- k_qk: S = T @ R^T (256x256, BK=64 core) + exp + fused s1/den partials ----
__global__ __launch_bounds__(512, 2) void k_qk(const unsigned short* __restrict__ Tb16,
                                               const unsigned short* __restrict__ Rb16,
                                               const float* __restrict__ vw,
                                               float* __restrict__ part_s1,
                                               float* __restrict__ part_den) {
  __shared__ __align__(16) char smem[131072];  // 2 slots x (A 32KB + B 32KB)
  __shared__ float vw_lds[256];
  __shared__ float red_s1[4][256], red_den[4][256];
  int t = threadIdx.x;
  // XCD swizzle: each XCD owns one batch (T+R panels fit its 4MB L2)
  int orig = blockIdx.x;
  int wgid = (orig & 7) * 64 + (orig >> 3);
  int b = wgid >> 6;
  int nb = ((wgid >> 3) & 7) * 256;
  int mb = (wgid & 7) * 256;
  if (t < 256) vw_lds[t] = vw[b * SEQ + mb + t];
  f32x4 acc[8][4] = {};
  gemm256_core(Tb16 + ((size_t)b * SEQ + nb) * DIM,
               Rb16 + ((size_t)b * SEQ + mb) * DIM, smem, acc);
  int lane = t & 63, w = t >> 6, wr = w >> 2, wc = w & 3;
  int lr = lane & 15, kq = lane >> 4;
  const float rs = 0.044194173824159216f;  // 1/sqrt(512)
  float vwl[4];
#pragma unroll
  for (int j = 0; j < 4; ++j) vwl[j] = vw_lds[wc * 64 + j * 16 + lr];
#pragma unroll
  for (int i = 0; i < 8; ++i) {
#pragma unroll
    for (int r = 0; r < 4; ++r) {
      float sa = 0.f, sd = 0.f;
#pragma unroll
      for (int j = 0; j < 4; ++j) {
        float e = __expf(acc[i][j][r] * rs);
        sa = fmaf(e, vwl[j], sa);
        sd += e;
      }
#pragma unroll
      for (int m = 1; m < 16; m <<= 1) { sa += __shfl_xor(sa, m); sd += __shfl_xor(sd, m); }
      if (lr == 0) {
        int rl = wr * 128 + i * 16 + kq * 4 + r;
        red_s1[wc][rl] = sa;
        red_den[wc][rl] = sd;
      }
    }
  }
  __syncthreads();
  if (t < 256) {
    size_t o = ((size_t)b * 8 + (mb >> 8)) * SEQ + nb + t;
    part_s1[o] = red_s1[0][t] + red_s1[1][t] + red_s1[2][t] + red_s1[3][t];
    part_den[o] = red_den[0][t] + red_den[1][t] + red_den[2][t] + red_den[3][t];
  }
}

// ---- k_final: winner = s1/den + const1 + c0 ----
__global__ void k_final(const float* __restrict__ part_s1, const float* __restrict__ part_den,
                        const float* __restrict__ consts, float* __restrict__ out) {
  int n = blockIdx.x * 256 + threadIdx.x;
  int b = n >> 11, nn = n & 2047;
  float s1 = 0.f, dn = 0.f;
#pragma unroll
  for (int i = 0; i < 8; ++i) {
    size_t o = ((size_t)b * 8 + i) * SEQ + nn;
    s1 += part_s1[o];
    dn += part_den[o];
  }
  out[n] = s1 / dn + consts[0] + consts[1];
}

extern "C" void kernel_launch(void* const* d_in, const int* in_sizes, int n_in,
                              void* d_out, int out_size, void* d_ws, size_t ws_size,
                              hipStream_t stream) {
  const float* R  = (const float*)d_in[0];
  const float* Wq = (const float*)d_in[1];
  const float* bq = (const float*)d_in[2];
  const float* Wk = (const float*)d_in[3];
  const float* bk = (const float*)d_in[4];  // cancels in row-softmax
  const float* Wv = (const float*)d_in[5];
  const float* bv = (const float*)d_in[6];
  const float* W1 = (const float*)d_in[7];
  const float* b1 = (const float*)d_in[8];
  const float* W2 = (const float*)d_in[9];
  const float* b2 = (const float*)d_in[10];
  (void)bk;
  float* out = (float*)d_out;

  char* p = (char*)d_ws;
  unsigned short* Rb16 = (unsigned short*)p; p += (size_t)MTOT * DIM * 2;
  unsigned short* Tb16 = (unsigned short*)p; p += (size_t)MTOT * DIM * 2;
  unsigned short* Gt   = (unsigned short*)p; p += (size_t)DIM * DIM * 2;
  float* part_s1  = (float*)p; p += (size_t)BATCH * 8 * SEQ * 4;
  float* part_den = (float*)p; p += (size_t)BATCH * 8 * SEQ * 4;
  float* u      = (float*)p; p += DIM * 4;
  float* wv2    = (float*)p; p += DIM * 4;
  float* vw     = (float*)p; p += MTOT * 4;
  float* consts = (float*)p; p += 16;

  hipLaunchKernelGGL(k_prep, dim3(321 + MTOT * DIM / (256 * 8)), dim3(256), 0, stream,
                     R, Wq, Wk, Wv, bq, bv, W1, b1, W2, b2, Gt, Rb16, u, wv2, consts);
  hipLaunchKernelGGL(k_projT, dim3(MTOT / 128, DIM / 128), dim3(256), 0, stream,
                     Rb16, Gt, u, wv2, Tb16, vw);
  hipLaunchKernelGGL(k_qk, dim3(512), dim3(512), 0, stream, Tb16, Rb16, vw, part_s1, part_den);
  hipLaunchKernelGGL(k_final, dim3(MTOT / 256), dim3(256), 0, stream,
                     part_s1, part_den, consts, out);
}